// Round 1
// baseline (838.491 us; speedup 1.0000x reference)
//
#include <hip/hip_runtime.h>

#define P 32
#define CIN 10
#define COUT 64
#define NG 5
#define EPSV 1e-3f

__device__ __forceinline__ int group_of(int nv) {
    return nv < 2 ? 0 : nv < 3 ? 1 : nv < 4 ? 2 : nv < 16 ? 3 : 4;
}

__device__ __forceinline__ float4 f4zero() { return make_float4(0.f, 0.f, 0.f, 0.f); }

// acc(4ch) = row[0..9] . w[0..9]   (row is 8B-aligned: p*10 floats)
__device__ __forceinline__ float4 dot_row(const float* __restrict__ row,
                                          const float4* __restrict__ w) {
    const float2* r = (const float2*)row;
    const float2 a0 = r[0], a1 = r[1], a2 = r[2], a3 = r[3], a4 = r[4];
    float4 acc;
    acc.x = a0.x * w[0].x; acc.y = a0.x * w[0].y; acc.z = a0.x * w[0].z; acc.w = a0.x * w[0].w;
    acc.x = fmaf(a0.y, w[1].x, acc.x); acc.y = fmaf(a0.y, w[1].y, acc.y);
    acc.z = fmaf(a0.y, w[1].z, acc.z); acc.w = fmaf(a0.y, w[1].w, acc.w);
    acc.x = fmaf(a1.x, w[2].x, acc.x); acc.y = fmaf(a1.x, w[2].y, acc.y);
    acc.z = fmaf(a1.x, w[2].z, acc.z); acc.w = fmaf(a1.x, w[2].w, acc.w);
    acc.x = fmaf(a1.y, w[3].x, acc.x); acc.y = fmaf(a1.y, w[3].y, acc.y);
    acc.z = fmaf(a1.y, w[3].z, acc.z); acc.w = fmaf(a1.y, w[3].w, acc.w);
    acc.x = fmaf(a2.x, w[4].x, acc.x); acc.y = fmaf(a2.x, w[4].y, acc.y);
    acc.z = fmaf(a2.x, w[4].z, acc.z); acc.w = fmaf(a2.x, w[4].w, acc.w);
    acc.x = fmaf(a2.y, w[5].x, acc.x); acc.y = fmaf(a2.y, w[5].y, acc.y);
    acc.z = fmaf(a2.y, w[5].z, acc.z); acc.w = fmaf(a2.y, w[5].w, acc.w);
    acc.x = fmaf(a3.x, w[6].x, acc.x); acc.y = fmaf(a3.x, w[6].y, acc.y);
    acc.z = fmaf(a3.x, w[6].z, acc.z); acc.w = fmaf(a3.x, w[6].w, acc.w);
    acc.x = fmaf(a3.y, w[7].x, acc.x); acc.y = fmaf(a3.y, w[7].y, acc.y);
    acc.z = fmaf(a3.y, w[7].z, acc.z); acc.w = fmaf(a3.y, w[7].w, acc.w);
    acc.x = fmaf(a4.x, w[8].x, acc.x); acc.y = fmaf(a4.x, w[8].y, acc.y);
    acc.z = fmaf(a4.x, w[8].z, acc.z); acc.w = fmaf(a4.x, w[8].w, acc.w);
    acc.x = fmaf(a4.y, w[9].x, acc.x); acc.y = fmaf(a4.y, w[9].y, acc.y);
    acc.z = fmaf(a4.y, w[9].z, acc.z); acc.w = fmaf(a4.y, w[9].w, acc.w);
    return acc;
}

// ---------------- Kernel A: per-group sum / sumsq / voxel count ----------------
__global__ __launch_bounds__(256) void stats_kernel(
    const float* __restrict__ inputs, const int* __restrict__ num,
    const float* __restrict__ W, float* __restrict__ gsum,
    float* __restrict__ gsq, float* __restrict__ gcnt, int N)
{
    __shared__ float Ws[NG * CIN * COUT];        // 12.8 KB
    __shared__ float4 redS[4][NG][16];           // wave-private slots
    __shared__ float4 redQ[4][NG][16];
    __shared__ int   redC[4][NG];

    const int tid = threadIdx.x;
    for (int i = tid; i < NG * CIN * COUT / 4; i += 256)
        ((float4*)Ws)[i] = ((const float4*)W)[i];
    for (int i = tid; i < 4 * NG * 16; i += 256) {
        ((float4*)redS)[i] = f4zero();
        ((float4*)redQ)[i] = f4zero();
    }
    if (tid < 4 * NG) ((int*)redC)[tid] = 0;
    __syncthreads();

    const int lane = tid & 63, wv = tid >> 6;
    const int c4 = lane & 15, pb = lane >> 4;
    const int gw = blockIdx.x * 4 + wv;
    const int stride = gridDim.x * 4;
    int cnt0 = 0, cnt1 = 0, cnt2 = 0, cnt3 = 0, cnt4 = 0;

    for (int v = gw; v < N; v += stride) {
        const int g = group_of(num[v]);
        const float* inrow = inputs + (size_t)v * (P * CIN);
        float4 w[CIN];
        const float4* Wg = (const float4*)(Ws + g * CIN * COUT);
        #pragma unroll
        for (int i = 0; i < CIN; ++i) w[i] = Wg[i * 16 + c4];

        float4 s = f4zero(), q = f4zero();
        #pragma unroll
        for (int k = 0; k < 8; ++k) {
            const int p = pb + k * 4;
            const float4 acc = dot_row(inrow + p * CIN, w);
            s.x += acc.x; s.y += acc.y; s.z += acc.z; s.w += acc.w;
            q.x = fmaf(acc.x, acc.x, q.x); q.y = fmaf(acc.y, acc.y, q.y);
            q.z = fmaf(acc.z, acc.z, q.z); q.w = fmaf(acc.w, acc.w, q.w);
        }
        #pragma unroll
        for (int msk = 16; msk <= 32; msk <<= 1) {
            s.x += __shfl_xor(s.x, msk); s.y += __shfl_xor(s.y, msk);
            s.z += __shfl_xor(s.z, msk); s.w += __shfl_xor(s.w, msk);
            q.x += __shfl_xor(q.x, msk); q.y += __shfl_xor(q.y, msk);
            q.z += __shfl_xor(q.z, msk); q.w += __shfl_xor(q.w, msk);
        }
        if (lane < 16) {
            float4 S = redS[wv][g][c4];
            S.x += s.x; S.y += s.y; S.z += s.z; S.w += s.w;
            redS[wv][g][c4] = S;
            float4 Q = redQ[wv][g][c4];
            Q.x += q.x; Q.y += q.y; Q.z += q.z; Q.w += q.w;
            redQ[wv][g][c4] = Q;
        }
        switch (g) {
            case 0: cnt0++; break; case 1: cnt1++; break; case 2: cnt2++; break;
            case 3: cnt3++; break; default: cnt4++; break;
        }
    }
    if (lane == 0) {
        redC[wv][0] = cnt0; redC[wv][1] = cnt1; redC[wv][2] = cnt2;
        redC[wv][3] = cnt3; redC[wv][4] = cnt4;
    }
    __syncthreads();

    if (tid < NG * 16) {
        const int g = tid >> 4, c = tid & 15;
        float4 S = redS[0][g][c], Q = redQ[0][g][c];
        #pragma unroll
        for (int wvi = 1; wvi < 4; ++wvi) {
            const float4 s2 = redS[wvi][g][c], q2 = redQ[wvi][g][c];
            S.x += s2.x; S.y += s2.y; S.z += s2.z; S.w += s2.w;
            Q.x += q2.x; Q.y += q2.y; Q.z += q2.z; Q.w += q2.w;
        }
        atomicAdd(&gsum[g * COUT + c * 4 + 0], S.x);
        atomicAdd(&gsum[g * COUT + c * 4 + 1], S.y);
        atomicAdd(&gsum[g * COUT + c * 4 + 2], S.z);
        atomicAdd(&gsum[g * COUT + c * 4 + 3], S.w);
        atomicAdd(&gsq[g * COUT + c * 4 + 0], Q.x);
        atomicAdd(&gsq[g * COUT + c * 4 + 1], Q.y);
        atomicAdd(&gsq[g * COUT + c * 4 + 2], Q.z);
        atomicAdd(&gsq[g * COUT + c * 4 + 3], Q.w);
    }
    if (tid < NG) {
        const int c = redC[0][tid] + redC[1][tid] + redC[2][tid] + redC[3][tid];
        if (c) atomicAdd(&gcnt[tid], (float)c);
    }
}

// ---------------- Kernel B: fold BN stats into scale/shift ----------------
__global__ __launch_bounds__(NG * COUT) void norm_kernel(
    const float* __restrict__ gsum, const float* __restrict__ gsq,
    const float* __restrict__ gcnt, const float* __restrict__ gamma,
    const float* __restrict__ beta, float* __restrict__ scale,
    float* __restrict__ shift)
{
    const int t = threadIdx.x;          // 320 threads; t = g*64 + c
    const int g = t >> 6;
    const float cnt = gcnt[g] * (float)P;
    const float denom = fmaxf(cnt, 1.f);
    const float mean = gsum[t] / denom;
    const float var = gsq[t] / denom - mean * mean;
    const float sc = gamma[t] * rsqrtf(var + EPSV);
    scale[t] = sc;
    shift[t] = fmaf(-mean, sc, beta[t]);
}

// ---------------- Kernel C: one voxel per wave ----------------
// Changes this round (write-path efficiency):
//  1. plain stores instead of nontemporal (fill kernel proves plain stores hit
//     6.2 TB/s; nt write-around on gfx950 is the prime suspect for our ~2-2.7 TB/s)
//  2. each store instruction now covers a fully CONTIGUOUS 1 KiB (two complete
//     512 B output rows: [x(2t) | max | x(2t+1) | max]) via an in-register
//     __shfl remap, instead of 4x256 B chunks strided 512 B in two passes.
__global__ __launch_bounds__(256) void out_kernel(
    const float* __restrict__ inputs, const int* __restrict__ num,
    const float* __restrict__ W, const float* __restrict__ scale,
    const float* __restrict__ shift, float* __restrict__ out, int N)
{
    const int tid = threadIdx.x;
    const int lane = tid & 63, wv = tid >> 6;
    const int c4 = lane & 15, pb = lane >> 4;
    const int v = blockIdx.x * 4 + wv;
    if (v >= N) return;

    // g is wave-uniform: pin it to an SGPR so W/scale/shift bases are scalar
    const int g = __builtin_amdgcn_readfirstlane(group_of(num[v]));

    // W fragment straight from global: 12.8 KB total, L1-resident, 4-way
    // same-address broadcast per load instruction
    const float4* Wg = (const float4*)W + g * (CIN * 16);
    float4 w[CIN];
    #pragma unroll
    for (int i = 0; i < CIN; ++i) w[i] = Wg[i * 16 + c4];
    const float4 sc = ((const float4*)scale)[g * 16 + c4];
    const float4 sh = ((const float4*)shift)[g * 16 + c4];

    const float* inrow = inputs + (size_t)v * (P * CIN);
    float4* outv = (float4*)out + (size_t)v * (P * 2 * COUT / 4);  // 1024 float4 per voxel

    // compute all 8 row-groups; this lane holds y for rows p = pb + 4k, ch 4*c4..
    float4 y[8];
    float4 m = f4zero();  // relu => 0 is a safe identity
    #pragma unroll
    for (int k = 0; k < 8; ++k) {
        const int p = pb + k * 4;
        const float4 acc = dot_row(inrow + p * CIN, w);
        float4 t;
        t.x = fmaxf(fmaf(acc.x, sc.x, sh.x), 0.f);
        t.y = fmaxf(fmaf(acc.y, sc.y, sh.y), 0.f);
        t.z = fmaxf(fmaf(acc.z, sc.z, sh.z), 0.f);
        t.w = fmaxf(fmaf(acc.w, sc.w, sh.w), 0.f);
        y[k] = t;
        m.x = fmaxf(m.x, t.x); m.y = fmaxf(m.y, t.y);
        m.z = fmaxf(m.z, t.z); m.w = fmaxf(m.w, t.w);
    }
    #pragma unroll
    for (int msk = 16; msk <= 32; msk <<= 1) {  // butterfly: all lanes get the max
        m.x = fmaxf(m.x, __shfl_xor(m.x, msk));
        m.y = fmaxf(m.y, __shfl_xor(m.y, msk));
        m.z = fmaxf(m.z, __shfl_xor(m.z, msk));
        m.w = fmaxf(m.w, __shfl_xor(m.w, msk));
    }

    // Store phase: instruction t covers rows 2t..2t+1 = float4 [t*64, t*64+64)
    // lane j: row = 2t + (j>>5); idx = j&31; idx<16 -> x-half (shuffled from the
    // lane that computed it: src = ((2t)&3)*16 + (j>>5)*16 + (j&15), reg k=t>>1);
    // idx>=16 -> per-channel max (every lane already holds m for its own c4).
    const int half16 = (lane >> 5) << 4;       // 0 or 16
    const bool useM = (lane & 16) != 0;        // idx >= 16
    #pragma unroll
    for (int t = 0; t < 16; ++t) {
        const int k = t >> 1;                  // register holding rows 2t,2t+1
        const int src = (((2 * t) & 3) << 4) + half16 + c4;
        float4 val;
        val.x = __shfl(y[k].x, src);
        val.y = __shfl(y[k].y, src);
        val.z = __shfl(y[k].z, src);
        val.w = __shfl(y[k].w, src);
        val.x = useM ? m.x : val.x;
        val.y = useM ? m.y : val.y;
        val.z = useM ? m.z : val.z;
        val.w = useM ? m.w : val.w;
        outv[t * 64 + lane] = val;             // contiguous 1 KiB per wave-instr
    }
}

extern "C" void kernel_launch(void* const* d_in, const int* in_sizes, int n_in,
                              void* d_out, int out_size, void* d_ws, size_t ws_size,
                              hipStream_t stream)
{
    (void)n_in; (void)out_size; (void)ws_size;
    const float* inputs = (const float*)d_in[0];
    const int*   num    = (const int*)d_in[1];
    const float* W      = (const float*)d_in[2];
    const float* gamma  = (const float*)d_in[3];
    const float* beta   = (const float*)d_in[4];
    float* out = (float*)d_out;
    const int N = in_sizes[1];

    float* ws    = (float*)d_ws;
    float* gsum  = ws;          // 320
    float* gsq   = ws + 320;    // 320
    float* gcnt  = ws + 640;    // 5 (pad to 656 for 16B alignment of scale)
    float* scale = ws + 656;    // 320
    float* shift = ws + 976;    // 320

    (void)hipMemsetAsync(d_ws, 0, 648 * sizeof(float), stream);

    int gridA = (N + 3) / 4;
    if (gridA > 1024) gridA = 1024;
    stats_kernel<<<gridA, 256, 0, stream>>>(inputs, num, W, gsum, gsq, gcnt, N);
    norm_kernel<<<1, NG * COUT, 0, stream>>>(gsum, gsq, gcnt, gamma, beta, scale, shift);
    int gridC = (N + 3) / 4;   // exactly one wave per voxel
    out_kernel<<<gridC, 256, 0, stream>>>(inputs, num, W, scale, shift, out, N);
}

// Round 2
// 803.121 us; speedup vs baseline: 1.0440x; 1.0440x over previous
//
#include <hip/hip_runtime.h>

#define P 32
#define CIN 10
#define COUT 64
#define NG 5
#define EPSV 1e-3f

typedef float nfloat4 __attribute__((ext_vector_type(4)));  // native vec for nontemporal builtins

__device__ __forceinline__ int group_of(int nv) {
    return nv < 2 ? 0 : nv < 3 ? 1 : nv < 4 ? 2 : nv < 16 ? 3 : 4;
}

__device__ __forceinline__ float4 f4zero() { return make_float4(0.f, 0.f, 0.f, 0.f); }

__device__ __forceinline__ void nt_store4(float4 v, float4* p) {
    nfloat4 t; t.x = v.x; t.y = v.y; t.z = v.z; t.w = v.w;
    __builtin_nontemporal_store(t, (nfloat4*)p);
}

// acc(4ch) = row[0..9] . w[0..9]   (row is 8B-aligned: p*10 floats)
__device__ __forceinline__ float4 dot_row(const float* __restrict__ row,
                                          const float4* __restrict__ w) {
    const float2* r = (const float2*)row;
    const float2 a0 = r[0], a1 = r[1], a2 = r[2], a3 = r[3], a4 = r[4];
    float4 acc;
    acc.x = a0.x * w[0].x; acc.y = a0.x * w[0].y; acc.z = a0.x * w[0].z; acc.w = a0.x * w[0].w;
    acc.x = fmaf(a0.y, w[1].x, acc.x); acc.y = fmaf(a0.y, w[1].y, acc.y);
    acc.z = fmaf(a0.y, w[1].z, acc.z); acc.w = fmaf(a0.y, w[1].w, acc.w);
    acc.x = fmaf(a1.x, w[2].x, acc.x); acc.y = fmaf(a1.x, w[2].y, acc.y);
    acc.z = fmaf(a1.x, w[2].z, acc.z); acc.w = fmaf(a1.x, w[2].w, acc.w);
    acc.x = fmaf(a1.y, w[3].x, acc.x); acc.y = fmaf(a1.y, w[3].y, acc.y);
    acc.z = fmaf(a1.y, w[3].z, acc.z); acc.w = fmaf(a1.y, w[3].w, acc.w);
    acc.x = fmaf(a2.x, w[4].x, acc.x); acc.y = fmaf(a2.x, w[4].y, acc.y);
    acc.z = fmaf(a2.x, w[4].z, acc.z); acc.w = fmaf(a2.x, w[4].w, acc.w);
    acc.x = fmaf(a2.y, w[5].x, acc.x); acc.y = fmaf(a2.y, w[5].y, acc.y);
    acc.z = fmaf(a2.y, w[5].z, acc.z); acc.w = fmaf(a2.y, w[5].w, acc.w);
    acc.x = fmaf(a3.x, w[6].x, acc.x); acc.y = fmaf(a3.x, w[6].y, acc.y);
    acc.z = fmaf(a3.x, w[6].z, acc.z); acc.w = fmaf(a3.x, w[6].w, acc.w);
    acc.x = fmaf(a3.y, w[7].x, acc.x); acc.y = fmaf(a3.y, w[7].y, acc.y);
    acc.z = fmaf(a3.y, w[7].z, acc.z); acc.w = fmaf(a3.y, w[7].w, acc.w);
    acc.x = fmaf(a4.x, w[8].x, acc.x); acc.y = fmaf(a4.x, w[8].y, acc.y);
    acc.z = fmaf(a4.x, w[8].z, acc.z); acc.w = fmaf(a4.x, w[8].w, acc.w);
    acc.x = fmaf(a4.y, w[9].x, acc.x); acc.y = fmaf(a4.y, w[9].y, acc.y);
    acc.z = fmaf(a4.y, w[9].z, acc.z); acc.w = fmaf(a4.y, w[9].w, acc.w);
    return acc;
}

// ---------------- Kernel A: per-group sum / sumsq / voxel count ----------------
__global__ __launch_bounds__(256) void stats_kernel(
    const float* __restrict__ inputs, const int* __restrict__ num,
    const float* __restrict__ W, float* __restrict__ gsum,
    float* __restrict__ gsq, float* __restrict__ gcnt, int N)
{
    __shared__ float Ws[NG * CIN * COUT];        // 12.8 KB
    __shared__ float4 redS[4][NG][16];           // wave-private slots
    __shared__ float4 redQ[4][NG][16];
    __shared__ int   redC[4][NG];

    const int tid = threadIdx.x;
    for (int i = tid; i < NG * CIN * COUT / 4; i += 256)
        ((float4*)Ws)[i] = ((const float4*)W)[i];
    for (int i = tid; i < 4 * NG * 16; i += 256) {
        ((float4*)redS)[i] = f4zero();
        ((float4*)redQ)[i] = f4zero();
    }
    if (tid < 4 * NG) ((int*)redC)[tid] = 0;
    __syncthreads();

    const int lane = tid & 63, wv = tid >> 6;
    const int c4 = lane & 15, pb = lane >> 4;
    const int gw = blockIdx.x * 4 + wv;
    const int stride = gridDim.x * 4;
    int cnt0 = 0, cnt1 = 0, cnt2 = 0, cnt3 = 0, cnt4 = 0;

    for (int v = gw; v < N; v += stride) {
        const int g = group_of(num[v]);
        const float* inrow = inputs + (size_t)v * (P * CIN);
        float4 w[CIN];
        const float4* Wg = (const float4*)(Ws + g * CIN * COUT);
        #pragma unroll
        for (int i = 0; i < CIN; ++i) w[i] = Wg[i * 16 + c4];

        float4 s = f4zero(), q = f4zero();
        #pragma unroll
        for (int k = 0; k < 8; ++k) {
            const int p = pb + k * 4;
            const float4 acc = dot_row(inrow + p * CIN, w);
            s.x += acc.x; s.y += acc.y; s.z += acc.z; s.w += acc.w;
            q.x = fmaf(acc.x, acc.x, q.x); q.y = fmaf(acc.y, acc.y, q.y);
            q.z = fmaf(acc.z, acc.z, q.z); q.w = fmaf(acc.w, acc.w, q.w);
        }
        #pragma unroll
        for (int msk = 16; msk <= 32; msk <<= 1) {
            s.x += __shfl_xor(s.x, msk); s.y += __shfl_xor(s.y, msk);
            s.z += __shfl_xor(s.z, msk); s.w += __shfl_xor(s.w, msk);
            q.x += __shfl_xor(q.x, msk); q.y += __shfl_xor(q.y, msk);
            q.z += __shfl_xor(q.z, msk); q.w += __shfl_xor(q.w, msk);
        }
        if (lane < 16) {
            float4 S = redS[wv][g][c4];
            S.x += s.x; S.y += s.y; S.z += s.z; S.w += s.w;
            redS[wv][g][c4] = S;
            float4 Q = redQ[wv][g][c4];
            Q.x += q.x; Q.y += q.y; Q.z += q.z; Q.w += q.w;
            redQ[wv][g][c4] = Q;
        }
        switch (g) {
            case 0: cnt0++; break; case 1: cnt1++; break; case 2: cnt2++; break;
            case 3: cnt3++; break; default: cnt4++; break;
        }
    }
    if (lane == 0) {
        redC[wv][0] = cnt0; redC[wv][1] = cnt1; redC[wv][2] = cnt2;
        redC[wv][3] = cnt3; redC[wv][4] = cnt4;
    }
    __syncthreads();

    if (tid < NG * 16) {
        const int g = tid >> 4, c = tid & 15;
        float4 S = redS[0][g][c], Q = redQ[0][g][c];
        #pragma unroll
        for (int wvi = 1; wvi < 4; ++wvi) {
            const float4 s2 = redS[wvi][g][c], q2 = redQ[wvi][g][c];
            S.x += s2.x; S.y += s2.y; S.z += s2.z; S.w += s2.w;
            Q.x += q2.x; Q.y += q2.y; Q.z += q2.z; Q.w += q2.w;
        }
        atomicAdd(&gsum[g * COUT + c * 4 + 0], S.x);
        atomicAdd(&gsum[g * COUT + c * 4 + 1], S.y);
        atomicAdd(&gsum[g * COUT + c * 4 + 2], S.z);
        atomicAdd(&gsum[g * COUT + c * 4 + 3], S.w);
        atomicAdd(&gsq[g * COUT + c * 4 + 0], Q.x);
        atomicAdd(&gsq[g * COUT + c * 4 + 1], Q.y);
        atomicAdd(&gsq[g * COUT + c * 4 + 2], Q.z);
        atomicAdd(&gsq[g * COUT + c * 4 + 3], Q.w);
    }
    if (tid < NG) {
        const int c = redC[0][tid] + redC[1][tid] + redC[2][tid] + redC[3][tid];
        if (c) atomicAdd(&gcnt[tid], (float)c);
    }
}

// ---------------- Kernel B: norm fold + output, one voxel per wave ----------------
// Round-2 changes:
//  * store scheme reverted to round-0 (nt stores, direct addressing) — the
//    round-1 shuffle remap cost +30 us of pure VALU/LDS overhead, confirming
//    the direct pattern was already write-efficient.
//  * norm_kernel fused in: each wave folds raw gsum/gsq/gcnt into its own
//    group's scale/shift (4 channels/lane, ~30 VALU + 5 L2-broadcast loads).
//    Saves one dispatch and the scale/shift global round-trip. Math identical
//    (same division / rsqrtf / fmaf sequence as the old norm_kernel).
__global__ __launch_bounds__(256) void out_kernel(
    const float* __restrict__ inputs, const int* __restrict__ num,
    const float* __restrict__ W,
    const float* __restrict__ gsum, const float* __restrict__ gsq,
    const float* __restrict__ gcnt,
    const float* __restrict__ gamma, const float* __restrict__ beta,
    float* __restrict__ out, int N)
{
    const int tid = threadIdx.x;
    const int lane = tid & 63, wv = tid >> 6;
    const int c4 = lane & 15, pb = lane >> 4;
    const int v = blockIdx.x * 4 + wv;
    if (v >= N) return;

    // g is wave-uniform: pin it to an SGPR so W/stat bases are scalar
    const int g = __builtin_amdgcn_readfirstlane(group_of(num[v]));

    // W fragment straight from global: 12.8 KB total, L1-resident, 4-way
    // same-address broadcast per load instruction
    const float4* Wg = (const float4*)W + g * (CIN * 16);
    float4 w[CIN];
    #pragma unroll
    for (int i = 0; i < CIN; ++i) w[i] = Wg[i * 16 + c4];

    // fold BN stats into scale/shift for this lane's 4 channels
    const float4 s4 = ((const float4*)gsum)[g * 16 + c4];
    const float4 q4 = ((const float4*)gsq)[g * 16 + c4];
    const float4 ga = ((const float4*)gamma)[g * 16 + c4];
    const float4 be = ((const float4*)beta)[g * 16 + c4];
    const float denom = fmaxf(gcnt[g] * (float)P, 1.f);
    float4 sc, sh;
    {
        const float mx = s4.x / denom, vx = q4.x / denom - mx * mx;
        sc.x = ga.x * rsqrtf(vx + EPSV); sh.x = fmaf(-mx, sc.x, be.x);
        const float my = s4.y / denom, vy = q4.y / denom - my * my;
        sc.y = ga.y * rsqrtf(vy + EPSV); sh.y = fmaf(-my, sc.y, be.y);
        const float mz = s4.z / denom, vz = q4.z / denom - mz * mz;
        sc.z = ga.z * rsqrtf(vz + EPSV); sh.z = fmaf(-mz, sc.z, be.z);
        const float mw = s4.w / denom, vw = q4.w / denom - mw * mw;
        sc.w = ga.w * rsqrtf(vw + EPSV); sh.w = fmaf(-mw, sc.w, be.w);
    }

    const float* inrow = inputs + (size_t)v * (P * CIN);
    float4* outv = (float4*)out + (size_t)v * (P * 2 * COUT / 4);  // 1024 float4 per voxel

    float4 m = f4zero();  // relu => 0 is a safe identity
    #pragma unroll
    for (int k = 0; k < 8; ++k) {
        const int p = pb + k * 4;
        const float4 acc = dot_row(inrow + p * CIN, w);
        float4 y;
        y.x = fmaxf(fmaf(acc.x, sc.x, sh.x), 0.f);
        y.y = fmaxf(fmaf(acc.y, sc.y, sh.y), 0.f);
        y.z = fmaxf(fmaf(acc.z, sc.z, sh.z), 0.f);
        y.w = fmaxf(fmaf(acc.w, sc.w, sh.w), 0.f);
        nt_store4(y, &outv[p * 32 + c4]);
        m.x = fmaxf(m.x, y.x); m.y = fmaxf(m.y, y.y);
        m.z = fmaxf(m.z, y.z); m.w = fmaxf(m.w, y.w);
    }
    #pragma unroll
    for (int msk = 16; msk <= 32; msk <<= 1) {  // butterfly: all lanes get the max
        m.x = fmaxf(m.x, __shfl_xor(m.x, msk));
        m.y = fmaxf(m.y, __shfl_xor(m.y, msk));
        m.z = fmaxf(m.z, __shfl_xor(m.z, msk));
        m.w = fmaxf(m.w, __shfl_xor(m.w, msk));
    }
    #pragma unroll
    for (int k = 0; k < 8; ++k) {
        const int p = pb + k * 4;
        nt_store4(m, &outv[p * 32 + 16 + c4]);
    }
}

extern "C" void kernel_launch(void* const* d_in, const int* in_sizes, int n_in,
                              void* d_out, int out_size, void* d_ws, size_t ws_size,
                              hipStream_t stream)
{
    (void)n_in; (void)out_size; (void)ws_size;
    const float* inputs = (const float*)d_in[0];
    const int*   num    = (const int*)d_in[1];
    const float* W      = (const float*)d_in[2];
    const float* gamma  = (const float*)d_in[3];
    const float* beta   = (const float*)d_in[4];
    float* out = (float*)d_out;
    const int N = in_sizes[1];

    float* ws    = (float*)d_ws;
    float* gsum  = ws;          // 320
    float* gsq   = ws + 320;    // 320
    float* gcnt  = ws + 640;    // 5

    (void)hipMemsetAsync(d_ws, 0, 648 * sizeof(float), stream);

    int gridA = (N + 3) / 4;
    if (gridA > 1024) gridA = 1024;
    stats_kernel<<<gridA, 256, 0, stream>>>(inputs, num, W, gsum, gsq, gcnt, N);
    int gridC = (N + 3) / 4;   // exactly one wave per voxel
    out_kernel<<<gridC, 256, 0, stream>>>(inputs, num, W, gsum, gsq, gcnt,
                                          gamma, beta, out, N);
}